// Round 16
// baseline (45.276 us; speedup 1.0000x reference)
//
#include <hip/hip_runtime.h>
#include <hip/hip_fp16.h>

#define NN   10000
#define NE   640000
#define IC   512
#define H    7
#define HP   8                     // padded g row stride (2x float4)
#define NCH  256                   // bucket chunks
#define CE   (NE / NCH)            // 2500 edges per chunk
#define RG   250                   // row ranges (buckets)
#define RN   40                    // nodes per range
#define CAP  3072                  // bucket capacity (mean 2560, +10 sigma)
#define GN   32                    // nodes per gather block (16-lane groups)
#define NGB  ((NN + GN - 1) / GN)  // 313 gather blocks

__device__ __forceinline__ float wave_sum(float v) {
    #pragma unroll
    for (int off = 32; off; off >>= 1) v += __shfl_xor(v, off);
    return v;
}

__device__ __forceinline__ float group16_sum(float v) {
    #pragma unroll
    for (int off = 1; off < 16; off <<= 1) v += __shfl_xor(v, off);
    return v;
}

// K0: pure bucket pass. Each block sorts its 2500-edge chunk by row-range in
// LDS and writes it to the FIXED slot gbuf2[chunk*CE] (coalesced, no global
// atomics), plus per-chunk {count, offset} tables.
__global__ __launch_bounds__(1024) void k_bucket(
    const int* __restrict__ row, const int* __restrict__ col,
    const float* __restrict__ ew, int* __restrict__ ghist,
    int* __restrict__ goffs, int2* __restrict__ gbuf2)
{
    __shared__ int   lhist[RG];
    __shared__ int   loffs[RG];
    __shared__ int   lcur[RG];
    __shared__ int2  st[CE];            // 20 KB
    const int tid = threadIdx.x;
    const int base = blockIdx.x * CE;
    if (tid < RG) lhist[tid] = 0;
    __syncthreads();
    int ex[3]; float ef[3];
    #pragma unroll
    for (int k = 0; k < 3; ++k) {
        const int i = tid + k * 1024;
        ex[k] = -1;
        if (i < CE) {
            const int e = base + i;
            const int r = row[e], c = col[e];
            const int rg = r / RN, rl = r - rg * RN;
            ex[k] = c | (rl << 14) | (rg << 20);
            ef[k] = ew[e];
            atomicAdd(&lhist[rg], 1);          // LDS
        }
    }
    __syncthreads();
    if (tid < 64) {                      // exclusive scan of 250 counts
        const int ln = tid;
        int t4[4]; int s4 = 0;
        #pragma unroll
        for (int k = 0; k < 4; ++k) {
            const int j = ln * 4 + k;
            t4[k] = (j < RG) ? lhist[j] : 0;
            s4 += t4[k];
        }
        int s = s4;
        #pragma unroll
        for (int off = 1; off < 64; off <<= 1) {
            const int t = __shfl_up(s, off);
            if (ln >= off) s += t;
        }
        int run = s - s4;
        #pragma unroll
        for (int k = 0; k < 4; ++k) {
            const int j = ln * 4 + k;
            if (j < RG) { loffs[j] = run; lcur[j] = run; }
            run += t4[k];
        }
    }
    __syncthreads();
    #pragma unroll
    for (int k = 0; k < 3; ++k) {
        if (ex[k] >= 0) {
            const int pos = atomicAdd(&lcur[ex[k] >> 20], 1);   // LDS
            st[pos] = make_int2(ex[k], __float_as_int(ef[k]));
        }
    }
    __syncthreads();
    #pragma unroll
    for (int k = 0; k < 3; ++k) {
        const int i = tid + k * 1024;
        if (i < CE) gbuf2[base + i] = st[i];
    }
    if (tid < RG) {
        ghist[blockIdx.x * RG + tid] = lhist[tid];
        goffs[blockIdx.x * RG + tid] = loffs[tid];
    }
}

// K1: per range b: stage the 256 per-chunk segments into LDS, mm1 (40 rows,
// overlaps the staging latency), deg -> dinv, in-place counting-sort by local
// row into packed 4B edges {col | fp16(ew)<<16}, write sorted bucket + nseg +
// g1 = dinv * h1. No global atomics.
__global__ __launch_bounds__(1024) void k_stage_sort_mm1(
    const int* __restrict__ ghist, const int* __restrict__ goffs,
    const int2* __restrict__ gbuf2, const float* __restrict__ x,
    const float* __restrict__ W1, float* __restrict__ dinv,
    float* __restrict__ g1, int2* __restrict__ nseg,
    unsigned int* __restrict__ gbuf)
{
    __shared__ int2  staged[CAP];       // 24 KB (reused as packed uint after)
    __shared__ float wls[IC * H];       // 14 KB
    __shared__ int   ccnt[NCH];
    __shared__ int   coff[NCH];
    __shared__ int   total_s;
    __shared__ int   lhist[RN];
    __shared__ float ldeg[RN];
    __shared__ int   loffs[RN];
    __shared__ int   lcur[RN];
    __shared__ float ldv[RN];
    __shared__ float htile[RN][HP];
    const int tid = threadIdx.x, b = blockIdx.x;
    const int wv = tid >> 6, ln = tid & 63;

    if (tid < NCH) ccnt[tid] = ghist[tid * RG + b];
    if (tid >= 256 && tid < 256 + RN) { lhist[tid - 256] = 0; ldeg[tid - 256] = 0.0f; }
    for (int i = tid; i < IC * H; i += 1024) wls[i] = W1[i];
    __syncthreads();
    if (tid < 64) {                      // exclusive scan of 256 chunk counts
        const int ln0 = tid;
        int t4[4]; int s4 = 0;
        #pragma unroll
        for (int k = 0; k < 4; ++k) { t4[k] = ccnt[ln0 * 4 + k]; s4 += t4[k]; }
        int s = s4;
        #pragma unroll
        for (int off = 1; off < 64; off <<= 1) {
            const int t = __shfl_up(s, off);
            if (ln0 >= off) s += t;
        }
        int run = s - s4;
        #pragma unroll
        for (int k = 0; k < 4; ++k) { coff[ln0 * 4 + k] = run; run += t4[k]; }
        if (ln0 == 63) total_s = run;
    }
    __syncthreads();
    {   // stage segments: 4 threads per chunk (scattered ~80B reads)
        const int c = tid >> 2;
        const int cn = ccnt[c], co = coff[c];
        const int src = c * CE + goffs[c * RG + b];
        for (int i = tid & 3; i < cn; i += 4) staged[co + i] = gbuf2[src + i];
    }
    {   // mm1: 40 rows over 16 waves — FMA work overlaps staging stalls
        for (int r0 = wv; r0 < RN; r0 += 16) {
            const int r = b * RN + r0;
            const float4* xr4 = (const float4*)(x + (size_t)r * IC);
            const float4 a0 = xr4[ln * 2], a1 = xr4[ln * 2 + 1];
            const float e8[8] = {a0.x, a0.y, a0.z, a0.w, a1.x, a1.y, a1.z, a1.w};
            const float* wb = &wls[ln * 8 * H];
            float acc[H] = {};
            #pragma unroll
            for (int m = 0; m < 8; ++m)
                #pragma unroll
                for (int c2 = 0; c2 < H; ++c2) acc[c2] += e8[m] * wb[m * H + c2];
            #pragma unroll
            for (int c2 = 0; c2 < H; ++c2) {
                const float v = wave_sum(acc[c2]);
                if (ln == 0) htile[r0][c2] = v;
            }
            if (ln == 0) htile[r0][7] = 0.0f;
        }
    }
    __syncthreads();
    const int cnt = total_s;
    int2 ed[3];
    #pragma unroll
    for (int k = 0; k < 3; ++k) {        // edges -> regs; bin counts + degree
        const int i = tid + k * 1024;
        ed[k] = make_int2(-1, 0);
        if (i < cnt) {
            ed[k] = staged[i];
            const int rl = (ed[k].x >> 14) & 63;
            atomicAdd(&lhist[rl], 1);
            atomicAdd(&ldeg[rl], __int_as_float(ed[k].y));
        }
    }
    __syncthreads();
    if (tid < 64) {                      // scan 40 bins
        int v = (tid < RN) ? lhist[tid] : 0;
        int s = v;
        #pragma unroll
        for (int off = 1; off < 64; off <<= 1) {
            const int t = __shfl_up(s, off);
            if (tid >= off) s += t;
        }
        if (tid < RN) { loffs[tid] = s - v; lcur[tid] = s - v; }
    } else if (tid >= 64 && tid < 64 + RN) {
        ldv[tid - 64] = rsqrtf(1.0f + ldeg[tid - 64]);
    }
    __syncthreads();
    unsigned int* stp = (unsigned int*)staged;   // in-place packed scatter
    #pragma unroll
    for (int k = 0; k < 3; ++k) {
        if (ed[k].x >= 0) {
            const int rl = (ed[k].x >> 14) & 63;
            const int pos = atomicAdd(&lcur[rl], 1);   // LDS
            const unsigned short wb16 =
                __half_as_ushort(__float2half_rn(__int_as_float(ed[k].y)));
            stp[pos] = (unsigned int)(ed[k].x & 16383) | ((unsigned int)wb16 << 16);
        }
    }
    __syncthreads();
    #pragma unroll
    for (int k = 0; k < 3; ++k) {        // packed sorted bucket out (coalesced)
        const int i = tid + k * 1024;
        if (i < cnt) gbuf[(size_t)b * CAP + i] = stp[i];
    }
    if (tid < RN) {
        dinv[b * RN + tid] = ldv[tid];
        nseg[b * RN + tid] = make_int2(loffs[tid], lhist[tid]);
    }
    if (tid < RN * HP) {
        const int n = tid >> 3;
        g1[(size_t)(b * RN) * HP + tid] = ldv[n] * htile[n][tid & 7];
    }
}

// K2/K3: gather, one node per 16-lane group (32 nodes/block, no atomics).
// Packed 4B edges: col = e & 16383, w = fp16 in bits 16-31. x4 unroll keeps
// 4 edge loads + 4 g-row loads in flight per lane (avg segment = 64 edges =
// exactly one full iteration of 4 x 16 lanes).
template <bool FUSE_MM2>
__global__ __launch_bounds__(512) void k_gather(
    const unsigned int* __restrict__ gbuf, const int2* __restrict__ nseg,
    const float* __restrict__ dinv, const float* __restrict__ g,
    const float* __restrict__ bias, const float* __restrict__ W2,
    float* __restrict__ out)
{
    __shared__ float asum[GN][HP];
    __shared__ float vals[GN][HP];
    __shared__ float ldv[GN];
    __shared__ float w2[H * H];
    __shared__ float bb[H];
    const int tid = threadIdx.x, b = blockIdx.x;
    const int gid = tid >> 4, q = tid & 15;             // 32 groups x 16 lanes
    const int gn = b * GN + gid;
    if (!FUSE_MM2 && b == 0 && tid == 511) out[(size_t)NN * H] = 0.0f;  // reg
    if (tid < GN && b * GN + tid < NN) ldv[tid] = dinv[b * GN + tid];
    if (FUSE_MM2 && tid >= 64 && tid < 64 + H * H) w2[tid - 64] = W2[tid - 64];
    if (tid >= 128 && tid < 128 + H) bb[tid - 128] = bias[tid - 128];
    __syncthreads();
    if (gn < NN) {
        const int2 seg = nseg[gn];
        const unsigned int* bk = gbuf + (size_t)(gn / RN) * CAP;
        const int kend = seg.x + seg.y;
        float acc[H] = {};
        for (int k = seg.x + q; k < kend; k += 64) {
            const int k1 = k + 16, k2 = k + 32, k3 = k + 48;
            const unsigned int e0 = bk[k];
            const unsigned int e1 = bk[k1 < kend ? k1 : k];
            const unsigned int e2 = bk[k2 < kend ? k2 : k];
            const unsigned int e3 = bk[k3 < kend ? k3 : k];
            const float w0 = __half2float(__ushort_as_half((unsigned short)(e0 >> 16)));
            float w1 = __half2float(__ushort_as_half((unsigned short)(e1 >> 16)));
            float w2_ = __half2float(__ushort_as_half((unsigned short)(e2 >> 16)));
            float w3 = __half2float(__ushort_as_half((unsigned short)(e3 >> 16)));
            if (k1 >= kend) w1 = 0.0f;
            if (k2 >= kend) w2_ = 0.0f;
            if (k3 >= kend) w3 = 0.0f;
            const float4* p0 = (const float4*)(g + (size_t)(e0 & 16383u) * HP);
            const float4* p1 = (const float4*)(g + (size_t)(e1 & 16383u) * HP);
            const float4* p2 = (const float4*)(g + (size_t)(e2 & 16383u) * HP);
            const float4* p3 = (const float4*)(g + (size_t)(e3 & 16383u) * HP);
            const float4 lo0 = p0[0], hi0 = p0[1];
            const float4 lo1 = p1[0], hi1 = p1[1];
            const float4 lo2 = p2[0], hi2 = p2[1];
            const float4 lo3 = p3[0], hi3 = p3[1];
            acc[0] += w0 * lo0.x + w1 * lo1.x + w2_ * lo2.x + w3 * lo3.x;
            acc[1] += w0 * lo0.y + w1 * lo1.y + w2_ * lo2.y + w3 * lo3.y;
            acc[2] += w0 * lo0.z + w1 * lo1.z + w2_ * lo2.z + w3 * lo3.z;
            acc[3] += w0 * lo0.w + w1 * lo1.w + w2_ * lo2.w + w3 * lo3.w;
            acc[4] += w0 * hi0.x + w1 * hi1.x + w2_ * hi2.x + w3 * hi3.x;
            acc[5] += w0 * hi0.y + w1 * hi1.y + w2_ * hi2.y + w3 * hi3.y;
            acc[6] += w0 * hi0.z + w1 * hi1.z + w2_ * hi2.z + w3 * hi3.z;
        }
        #pragma unroll
        for (int j = 0; j < H; ++j) {
            const float s = group16_sum(acc[j]);
            if (q == 0) asum[gid][j] = s;
        }
    }
    __syncthreads();
    if (tid < GN * H) {
        const int n = tid / H, k = tid - n * H;
        const int node = b * GN + n;
        if (node < NN)
            vals[n][k] = ldv[n] * (asum[n][k] + g[(size_t)node * HP + k]) + bb[k];
    }
    __syncthreads();
    if (tid < GN * H) {
        const int n = tid / H, k = tid - n * H;
        const int node = b * GN + n;
        if (node < NN) {
            if (FUSE_MM2) {
                float o = 0.0f;
                #pragma unroll
                for (int j = 0; j < H; ++j) o += vals[n][j] * w2[j * H + k];
                out[(size_t)node * HP + k] = ldv[n] * o;   // g2 = dinv*(v@W2)
            } else {
                out[(size_t)node * H + k] = vals[n][k];    // final, stride 7
            }
        }
    }
    if (FUSE_MM2 && tid >= 256 && tid < 256 + GN) {
        const int node = b * GN + (tid - 256);
        if (node < NN) out[(size_t)node * HP + 7] = 0.0f;
    }
}

extern "C" void kernel_launch(void* const* d_in, const int* in_sizes, int n_in,
                              void* d_out, int out_size, void* d_ws, size_t ws_size,
                              hipStream_t stream) {
    const float* x  = (const float*)d_in[0];
    const int*   ei = (const int*)d_in[1];
    const float* ea = (const float*)d_in[2];
    const float* W1 = (const float*)d_in[4];
    const float* b1 = (const float*)d_in[5];
    const float* W2 = (const float*)d_in[6];
    const float* b2 = (const float*)d_in[7];
    float* out = (float*)d_out;

    char* p = (char*)d_ws;
    int* ghist = (int*)p;                 p += sizeof(int) * NCH * RG;
    int* goffs = (int*)p;                 p += sizeof(int) * NCH * RG;
    int2* gbuf2 = (int2*)p;               p += sizeof(int2) * NE;       // 5.12 MB
    unsigned int* gbuf = (unsigned int*)p; p += sizeof(unsigned int) * RG * CAP; // 3.07 MB
    int2* nseg = (int2*)p;                p += sizeof(int2) * NN;
    float* g1 = (float*)p;                p += sizeof(float) * NN * HP;
    float* g2 = (float*)p;                p += sizeof(float) * NN * HP;
    float* dinv = (float*)p;              p += sizeof(float) * NN;

    const int* row = ei;
    const int* col = ei + NE;

    k_bucket<<<NCH, 1024, 0, stream>>>(row, col, ea, ghist, goffs, gbuf2);
    k_stage_sort_mm1<<<RG, 1024, 0, stream>>>(ghist, goffs, gbuf2, x, W1,
                                              dinv, g1, nseg, gbuf);
    k_gather<true><<<NGB, 512, 0, stream>>>(gbuf, nseg, dinv, g1, b1, W2, g2);
    k_gather<false><<<NGB, 512, 0, stream>>>(gbuf, nseg, dinv, g2, b2, nullptr, out);
}